// Round 1
// baseline (553.068 us; speedup 1.0000x reference)
//
#include <hip/hip_runtime.h>

// Powderworld BehaviorFluidFlow: B=16, C=20, H=512, W=512, fp32.
// Two fall passes (left then right) reduce to a composed gather along W:
//   out[c][x] = world[c][ s1[s2[x]] ]   for all 20 channels,
// with channel 6 overridden by positional new_fluid_momentum where final
// cell id is a fluid. Decisions use only channels 0,1,2,6,8 + rand_movement.

#define WW 512
#define HH 512
#define CC 20
#define BB 16

__device__ __forceinline__ bool is_fluid_id(float id) {
    // empty=0, water=3, gas=9, lava=8, acid=12, agentKangaroo=14, agentLemming=15
    return (id == 0.0f) | (id == 3.0f) | (id == 9.0f) | (id == 8.0f) |
           (id == 12.0f) | (id == 14.0f) | (id == 15.0f);
}

__global__ __launch_bounds__(512)
void fluid_flow_kernel(const float* __restrict__ world,
                       const float* __restrict__ rand_movement,
                       float* __restrict__ out) {
    __shared__ float id_s[WW];
    __shared__ float den_s[WW];
    __shared__ float grav_s[WW];
    __shared__ float mom_s[WW];
    __shared__ float didg_s[WW];
    __shared__ float rm_s[WW];
    __shared__ int   dbl_s[WW];   // reused: pass-1 then pass-2 does_become_left
    __shared__ int   s1_s[WW];    // pass-1 source index

    const int row = blockIdx.x;            // 0 .. B*H-1
    const int b   = row >> 9;              // row / 512
    const int h   = row & (HH - 1);
    const int x   = threadIdx.x;           // 0 .. 511

    const size_t planeHW = (size_t)HH * WW;                       // per-channel plane
    const size_t baseRow = ((size_t)b * CC * HH + (size_t)h) * WW; // channel-0 row base

    // ---- stage decision channels ----
    id_s[x]   = world[baseRow + 0 * planeHW + x];
    den_s[x]  = world[baseRow + 1 * planeHW + x];
    grav_s[x] = world[baseRow + 2 * planeHW + x];
    mom_s[x]  = world[baseRow + 6 * planeHW + x];
    didg_s[x] = world[baseRow + 8 * planeHW + x];
    rm_s[x]   = rand_movement[((size_t)b * HH + (size_t)h) * WW + x];
    __syncthreads();

    // ---- pass 1 (fall_left = true): does_become_left ----
    {
        const float fd  = rm_s[x] + mom_s[x];          // + nfm(=0), matches (a+b)+c
        const bool matching = fd > 0.5f;               // fall_dir
        const float idc = id_s[x];
        const bool ia = (idc == 14.0f) | (idc == 15.0f);
        const bool ie = (idc == 0.0f) | (idc == 3.0f) | (idc == 9.0f) |
                        (idc == 8.0f) | (idc == 12.0f) | ia;
        const int  xl  = (x - 1) & (WW - 1);           // world_left = roll(shift=1)
        const bool ldl = (den_s[x] - den_s[xl]) > 0.0f;
        const bool ig  = grav_s[x]  == 1.0f;
        const bool ilg = grav_s[xl] == 1.0f;
        const bool ndg = (!(didg_s[x] > 0.0f)) | ia;
        dbl_s[x] = (matching & ie & ndg & ldl & ilg & ig) ? 1 : 0;
    }
    __syncthreads();

    // ---- pass-1 resolution: s1, momentum contribution ----
    float nfm;
    {
        const int d0 = dbl_s[x];
        const int d1 = dbl_s[(x + 1) & (WW - 1)];
        const int d2 = dbl_s[(x + 2) & (WW - 1)];
        const bool a1 = d0 && !d1;                     // take from left neighbor
        const bool b1 = d1 && !d2;                     // take from right neighbor
        s1_s[x] = a1 ? ((x - 1) & (WW - 1)) : (b1 ? ((x + 1) & (WW - 1)) : x);
        nfm = b1 ? 2.0f : 0.0f;
    }
    __syncthreads();

    // ---- pass 2 (fall_left = false) on world1 = world0[s1] ----
    {
        const int c = s1_s[x];
        const int l = s1_s[(x + 1) & (WW - 1)];        // world_left = roll(shift=-1)
        const float fd = (rm_s[x] + mom_s[c]) + nfm;   // left-assoc like the ref
        const bool matching = !(fd > 0.5f);            // ~fall_dir
        const float idc = id_s[c];
        const bool ia = (idc == 14.0f) | (idc == 15.0f);
        const bool ie = (idc == 0.0f) | (idc == 3.0f) | (idc == 9.0f) |
                        (idc == 8.0f) | (idc == 12.0f) | ia;
        const bool ldl = (den_s[c] - den_s[l]) > 0.0f;
        const bool ig  = grav_s[c] == 1.0f;
        const bool ilg = grav_s[l] == 1.0f;
        const bool ndg = (!(didg_s[c] > 0.0f)) | ia;
        const bool d = matching & ie & ndg & ldl & ilg & ig;
        __syncthreads();                               // everyone done reading pass-1 dbl_s
        dbl_s[x] = d ? 1 : 0;
    }
    __syncthreads();

    // ---- pass-2 resolution: composed source + final momentum ----
    int   sx;
    float nfm_final;
    {
        const int d0  = dbl_s[x];
        const int dm1 = dbl_s[(x - 1) & (WW - 1)];
        const int dm2 = dbl_s[(x - 2) & (WW - 1)];
        const bool a2 = d0  && !dm1;                   // take from x+1 of world1
        const bool b2 = dm1 && !dm2;                   // take from x-1 of world1
        const int s2  = a2 ? ((x + 1) & (WW - 1)) : (b2 ? ((x - 1) & (WW - 1)) : x);
        sx = s1_s[s2];
        nfm_final = nfm + (b2 ? -2.0f : 0.0f);
    }

    // ---- epilogue: gather all 20 channels; fix channel 6 ----
    const float fid   = id_s[sx];
    const bool  fluid = is_fluid_id(fid);

    out[baseRow + 0 * planeHW + x] = fid;
    out[baseRow + 1 * planeHW + x] = den_s[sx];
    out[baseRow + 2 * planeHW + x] = grav_s[sx];
    out[baseRow + 6 * planeHW + x] = fluid ? nfm_final : mom_s[sx];
    out[baseRow + 8 * planeHW + x] = didg_s[sx];

    #pragma unroll
    for (int c = 0; c < CC; ++c) {
        if (c == 0 || c == 1 || c == 2 || c == 6 || c == 8) continue;
        out[baseRow + (size_t)c * planeHW + x] = world[baseRow + (size_t)c * planeHW + sx];
    }
}

extern "C" void kernel_launch(void* const* d_in, const int* in_sizes, int n_in,
                              void* d_out, int out_size, void* d_ws, size_t ws_size,
                              hipStream_t stream) {
    const float* world = (const float*)d_in[0];
    const float* rm    = (const float*)d_in[1];
    // d_in[2] (rand_interact) and d_in[3] (rand_element) are unused by the reference.
    float* out = (float*)d_out;

    dim3 grid(BB * HH);   // 8192 rows
    dim3 block(WW);       // 512 threads, one cell each
    fluid_flow_kernel<<<grid, block, 0, stream>>>(world, rm, out);
}